// Round 1
// baseline (228.458 us; speedup 1.0000x reference)
//
#include <hip/hip_runtime.h>
#include <hip/hip_bf16.h>

// ---------------------------------------------------------------------------
// MoE forward (B=4,S=2048,D=512,H=512,E=8, top-2):
//   gate (fp64 logits) -> route -> grouped GEMM1 (f16 MFMA, relu) ->
//   grouped GEMM2 -> LayerNorm + weighted combine.
// Only the 2 selected experts per token are computed (4x fewer FLOPs than ref).
// ---------------------------------------------------------------------------

#define T_TOK   8192
#define DDIM    512
#define HDIM    512
#define NEXP    8
#define NASSIGN (T_TOK * 2)

typedef _Float16 f16x8 __attribute__((ext_vector_type(8)));
typedef float    f32x4 __attribute__((ext_vector_type(4)));

// ---------------- weight transpose + fp32->f16 cast ------------------------
// z < 8 : W1[e] [D][H] -> W1t[e] [H][D] ; z >= 8 : W2[e] [H][D] -> W2t[e] [D][H]
__global__ void transw_kernel(const float* __restrict__ W1,
                              const float* __restrict__ W2,
                              _Float16* __restrict__ W1t,
                              _Float16* __restrict__ W2t) {
    __shared__ float tile[32][33];
    int z = blockIdx.z;
    const float* src;
    _Float16* dst;
    if (z < 8) { src = W1 + (size_t)z * 512 * 512; dst = W1t + (size_t)z * 512 * 512; }
    else       { src = W2 + (size_t)(z - 8) * 512 * 512; dst = W2t + (size_t)(z - 8) * 512 * 512; }
    int bx = blockIdx.x * 32;   // src col
    int by = blockIdx.y * 32;   // src row
    int tx = threadIdx.x, ty = threadIdx.y;
#pragma unroll
    for (int i = 0; i < 4; i++) {
        int r = by + ty + i * 8;
        tile[ty + i * 8][tx] = src[(size_t)r * 512 + bx + tx];
    }
    __syncthreads();
#pragma unroll
    for (int i = 0; i < 4; i++) {
        int r = bx + ty + i * 8;
        dst[(size_t)r * 512 + by + tx] = (_Float16)tile[tx][ty + i * 8];
    }
}

// ---------------- gating: fp64 logits, top-2, softmax; also cast x->f16 ----
__global__ void gate_kernel(const float* __restrict__ x,
                            const float* __restrict__ Wg,
                            _Float16* __restrict__ xh,
                            int* __restrict__ ei,
                            float* __restrict__ gw,
                            int* __restrict__ counts) {
    __shared__ int lcnt[NEXP];
    if (threadIdx.x < NEXP) lcnt[threadIdx.x] = 0;
    __syncthreads();
    int lane = threadIdx.x & 63;
    int wave = threadIdx.x >> 6;

    for (int t = blockIdx.x * 4 + wave; t < T_TOK; t += gridDim.x * 4) {
        const float* xr = x + (size_t)t * DDIM + lane * 8;
        float4 xa = *(const float4*)(xr);
        float4 xb = *(const float4*)(xr + 4);
        float xv[8] = {xa.x, xa.y, xa.z, xa.w, xb.x, xb.y, xb.z, xb.w};
        f16x8 hv;
#pragma unroll
        for (int j = 0; j < 8; j++) hv[j] = (_Float16)xv[j];
        *(f16x8*)(xh + (size_t)t * DDIM + lane * 8) = hv;

        double acc[NEXP];
#pragma unroll
        for (int e = 0; e < NEXP; e++) acc[e] = 0.0;
#pragma unroll
        for (int jj = 0; jj < 8; jj++) {
            int d = lane * 8 + jj;
            const float4* wr = (const float4*)(Wg + (size_t)d * NEXP);
            float4 w0 = wr[0], w1 = wr[1];
            float wv[8] = {w0.x, w0.y, w0.z, w0.w, w1.x, w1.y, w1.z, w1.w};
#pragma unroll
            for (int e = 0; e < NEXP; e++) acc[e] += (double)xv[jj] * (double)wv[e];
        }
#pragma unroll
        for (int off = 1; off < 64; off <<= 1) {
#pragma unroll
            for (int e = 0; e < NEXP; e++) acc[e] += __shfl_xor(acc[e], off, 64);
        }
        if (lane == 0) {
            double v0 = -1e300; int i0 = 0;
#pragma unroll
            for (int e = 0; e < NEXP; e++) if (acc[e] > v0) { v0 = acc[e]; i0 = e; }
            double v1 = -1e300; int i1 = (i0 == 0) ? 1 : 0;
#pragma unroll
            for (int e = 0; e < NEXP; e++) if (e != i0 && acc[e] > v1) { v1 = acc[e]; i1 = e; }
            double ex = exp(v1 - v0);   // <= 1
            float g0 = (float)(1.0 / (1.0 + ex));
            float g1 = (float)(ex / (1.0 + ex));
            ei[2 * t] = i0;  ei[2 * t + 1] = i1;
            gw[2 * t] = g0;  gw[2 * t + 1] = g1;
            atomicAdd(&lcnt[i0], 1);
            atomicAdd(&lcnt[i1], 1);
        }
    }
    __syncthreads();
    if (threadIdx.x < NEXP) atomicAdd(&counts[threadIdx.x], lcnt[threadIdx.x]);
}

// ---------------- 8-entry exclusive prefix ---------------------------------
__global__ void prefix_kernel(const int* __restrict__ counts,
                              int* __restrict__ offsets,
                              int* __restrict__ cursor) {
    if (threadIdx.x == 0) {
        int s = 0;
        for (int e = 0; e < NEXP; e++) { offsets[e] = s; cursor[e] = s; s += counts[e]; }
    }
}

// ---------------- scatter: wave-aggregated bucket append -------------------
__global__ void scatter_kernel(const int* __restrict__ ei,
                               int* __restrict__ cursor,
                               int* __restrict__ rowtok,
                               int* __restrict__ pos) {
    int t = blockIdx.x * 256 + threadIdx.x;   // grid = 32 blocks, exact cover
    int lane = threadIdx.x & 63;
#pragma unroll
    for (int k = 0; k < 2; k++) {
        int s = 2 * t + k;
        int e = ei[s];
        int r = 0;
#pragma unroll
        for (int ex = 0; ex < NEXP; ex++) {
            unsigned long long mask = __ballot(e == ex);
            if (e == ex) {
                int leader = __ffsll((unsigned long long)mask) - 1;
                int cnt = __popcll(mask);
                unsigned long long below = mask & ((lane == 63) ? 0x7fffffffffffffffull
                                                                : ((1ull << lane) - 1ull));
                int base = 0;
                if (lane == leader) base = atomicAdd(&cursor[ex], cnt);
                base = __shfl(base, leader, 64);
                r = base + __popcll(below);
            }
        }
        rowtok[r] = s;
        pos[s] = r;
    }
}

// ---------------- grouped GEMM: C[r][n] = act(A[r] . Bt[n] + bias[n]) ------
// 128x128 tile, BK=32, 4 waves (2x2 of 64x64), mfma_f32_16x16x32_f16.
template <bool GATHER, bool RELU>
__global__ __launch_bounds__(256) void gemm_tile(
    const _Float16* __restrict__ A,     // xh [T][512] (gather) or hb rows
    const _Float16* __restrict__ Bt,    // [E][N=512][K=512] f16 (pre-transposed)
    const float* __restrict__ bias,     // [E][512]
    const int* __restrict__ rowtok,     // assignment -> token*2+k (gather only)
    const int* __restrict__ counts,
    const int* __restrict__ offsets,
    _Float16* __restrict__ C)           // [NASSIGN][512]
{
    int e = blockIdx.z;
    int ne = counts[e];
    int m0 = blockIdx.y * 128;
    if (m0 >= ne) return;
    int off = offsets[e];
    int n0 = blockIdx.x * 128;
    const _Float16* Bte = Bt + (size_t)e * 512 * 512;

    __shared__ _Float16 As[128 * 32];
    __shared__ _Float16 Bs[128 * 32];

    int tid = threadIdx.x;
    int lane = tid & 63;
    int wave = tid >> 6;
    int wm = (wave >> 1) * 64;
    int wn = (wave & 1) * 64;
    int quad = lane >> 4;
    int l16 = lane & 15;

    int srow = tid >> 2;      // 0..63
    int schunk = tid & 3;     // 16B chunk within BK row

    int r0g = m0 + srow;
    int r1g = m0 + srow + 64;
    int cr0 = off + (r0g < ne - 1 ? r0g : ne - 1);
    int cr1 = off + (r1g < ne - 1 ? r1g : ne - 1);
    const _Float16* arow0;
    const _Float16* arow1;
    if (GATHER) {
        arow0 = A + (size_t)(rowtok[cr0] >> 1) * 512;
        arow1 = A + (size_t)(rowtok[cr1] >> 1) * 512;
    } else {
        arow0 = A + (size_t)cr0 * 512;
        arow1 = A + (size_t)cr1 * 512;
    }
    const _Float16* brow0 = Bte + (size_t)(n0 + srow) * 512;
    const _Float16* brow1 = Bte + (size_t)(n0 + srow + 64) * 512;

    f32x4 acc[4][4];
#pragma unroll
    for (int i = 0; i < 4; i++)
#pragma unroll
        for (int j = 0; j < 4; j++) {
            acc[i][j][0] = 0.f; acc[i][j][1] = 0.f;
            acc[i][j][2] = 0.f; acc[i][j][3] = 0.f;
        }

    for (int k0 = 0; k0 < 512; k0 += 32) {
        uint4 a0 = *(const uint4*)(arow0 + k0 + schunk * 8);
        uint4 a1 = *(const uint4*)(arow1 + k0 + schunk * 8);
        uint4 b0 = *(const uint4*)(brow0 + k0 + schunk * 8);
        uint4 b1 = *(const uint4*)(brow1 + k0 + schunk * 8);
        __syncthreads();   // previous iteration's LDS reads done
        *(uint4*)(&As[srow * 32 + schunk * 8]) = a0;
        *(uint4*)(&As[(srow + 64) * 32 + schunk * 8]) = a1;
        *(uint4*)(&Bs[srow * 32 + schunk * 8]) = b0;
        *(uint4*)(&Bs[(srow + 64) * 32 + schunk * 8]) = b1;
        __syncthreads();

        f16x8 af[4], bf[4];
#pragma unroll
        for (int i = 0; i < 4; i++)
            af[i] = *(const f16x8*)(&As[(wm + i * 16 + l16) * 32 + quad * 8]);
#pragma unroll
        for (int j = 0; j < 4; j++)
            bf[j] = *(const f16x8*)(&Bs[(wn + j * 16 + l16) * 32 + quad * 8]);
#pragma unroll
        for (int i = 0; i < 4; i++)
#pragma unroll
            for (int j = 0; j < 4; j++)
                acc[i][j] = __builtin_amdgcn_mfma_f32_16x16x32_f16(af[i], bf[j], acc[i][j], 0, 0, 0);
    }

    // epilogue: D[row=quad*4+reg][col=l16]
    float bcol[4];
#pragma unroll
    for (int j = 0; j < 4; j++) bcol[j] = bias[(size_t)e * 512 + n0 + wn + j * 16 + l16];
#pragma unroll
    for (int i = 0; i < 4; i++) {
#pragma unroll
        for (int rr = 0; rr < 4; rr++) {
            int rg = m0 + wm + i * 16 + quad * 4 + rr;
            if (rg < ne) {
#pragma unroll
                for (int j = 0; j < 4; j++) {
                    float v = acc[i][j][rr] + bcol[j];
                    if (RELU) v = fmaxf(v, 0.0f);
                    C[(size_t)(off + rg) * 512 + n0 + wn + j * 16 + l16] = (_Float16)v;
                }
            }
        }
    }
}

// ---------------- LayerNorm + gate-weighted combine (1 wave / token) -------
__global__ void ln_combine_kernel(const _Float16* __restrict__ yb,
                                  const int* __restrict__ pos,
                                  const float* __restrict__ gw,
                                  const int* __restrict__ ei,
                                  const float* __restrict__ gamma,
                                  const float* __restrict__ beta,
                                  float* __restrict__ out) {
    int t = blockIdx.x * 4 + (threadIdx.x >> 6);
    int lane = threadIdx.x & 63;
    float o[8];
#pragma unroll
    for (int j = 0; j < 8; j++) o[j] = 0.0f;

#pragma unroll
    for (int k = 0; k < 2; k++) {
        int s = 2 * t + k;
        int r = pos[s];
        int e = ei[s];
        float w = gw[s];
        f16x8 v = *(const f16x8*)(yb + (size_t)r * 512 + lane * 8);
        float f[8];
        float sum = 0.f, sq = 0.f;
#pragma unroll
        for (int j = 0; j < 8; j++) { f[j] = (float)v[j]; sum += f[j]; sq += f[j] * f[j]; }
#pragma unroll
        for (int off = 1; off < 64; off <<= 1) {
            sum += __shfl_xor(sum, off, 64);
            sq  += __shfl_xor(sq, off, 64);
        }
        float mu = sum * (1.0f / 512.0f);
        float var = sq * (1.0f / 512.0f) - mu * mu;
        float rstd = rsqrtf(var + 1e-5f);
#pragma unroll
        for (int j = 0; j < 8; j++) {
            int d = lane * 8 + j;
            o[j] += w * ((f[j] - mu) * rstd * gamma[(size_t)e * 512 + d] + beta[(size_t)e * 512 + d]);
        }
    }
    float4* op = (float4*)(out + (size_t)t * 512 + lane * 8);
    op[0] = make_float4(o[0], o[1], o[2], o[3]);
    op[1] = make_float4(o[4], o[5], o[6], o[7]);
}

// ---------------------------------------------------------------------------
extern "C" void kernel_launch(void* const* d_in, const int* in_sizes, int n_in,
                              void* d_out, int out_size, void* d_ws, size_t ws_size,
                              hipStream_t stream) {
    const float* x     = (const float*)d_in[0];
    const float* Wg    = (const float*)d_in[1];
    const float* W1    = (const float*)d_in[2];
    const float* b1    = (const float*)d_in[3];
    const float* W2    = (const float*)d_in[4];
    const float* b2    = (const float*)d_in[5];
    const float* gamma = (const float*)d_in[6];
    const float* beta  = (const float*)d_in[7];
    float* out = (float*)d_out;

    // workspace carve-up (256B aligned)
    char* w = (char*)d_ws;
    size_t o = 0;
    auto alloc = [&](size_t bytes) -> void* {
        void* p = w + o;
        o += (bytes + 255) & ~(size_t)255;
        return p;
    };
    _Float16* xh  = (_Float16*)alloc((size_t)T_TOK * DDIM * 2);
    _Float16* W1t = (_Float16*)alloc((size_t)NEXP * DDIM * HDIM * 2);
    _Float16* W2t = (_Float16*)alloc((size_t)NEXP * DDIM * HDIM * 2);
    _Float16* hb  = (_Float16*)alloc((size_t)NASSIGN * HDIM * 2);
    _Float16* yb  = (_Float16*)alloc((size_t)NASSIGN * DDIM * 2);
    float* gw     = (float*)alloc((size_t)NASSIGN * 4);
    int* ei       = (int*)alloc((size_t)NASSIGN * 4);
    int* rowtok   = (int*)alloc((size_t)NASSIGN * 4);
    int* pos      = (int*)alloc((size_t)NASSIGN * 4);
    int* counts   = (int*)alloc(NEXP * 4);
    int* offsets  = (int*)alloc(NEXP * 4);
    int* cursor   = (int*)alloc(NEXP * 4);
    (void)ws_size; (void)n_in; (void)in_sizes; (void)out_size;

    hipMemsetAsync(counts, 0, NEXP * sizeof(int), stream);

    transw_kernel<<<dim3(16, 16, 16), dim3(32, 8), 0, stream>>>(W1, W2, W1t, W2t);
    gate_kernel<<<256, 256, 0, stream>>>(x, Wg, xh, ei, gw, counts);
    prefix_kernel<<<1, 64, 0, stream>>>(counts, offsets, cursor);
    scatter_kernel<<<32, 256, 0, stream>>>(ei, cursor, rowtok, pos);

    dim3 ggrid(4, 64, 8);   // n-tiles, max m-tiles (8192/128), experts
    gemm_tile<true, true><<<ggrid, 256, 0, stream>>>(xh, W1t, b1, rowtok, counts, offsets, hb);
    gemm_tile<false, false><<<ggrid, 256, 0, stream>>>(hb, W2t, b2, nullptr, counts, offsets, yb);

    ln_combine_kernel<<<2048, 256, 0, stream>>>(yb, pos, gw, ei, gamma, beta, out);
}

// Round 2
// 188.084 us; speedup vs baseline: 1.2147x; 1.2147x over previous
//
#include <hip/hip_runtime.h>
#include <hip/hip_bf16.h>

// ---------------------------------------------------------------------------
// MoE forward (B=4,S=2048,D=512,H=512,E=8, top-2):
//   gate (fp64 logits, 1 token/wave) -> histogram -> prefix -> scatter ->
//   grouped GEMM1 (f16 MFMA, async LDS staging, relu) -> grouped GEMM2 ->
//   LayerNorm + weighted combine.
// Only the 2 selected experts per token are computed (4x fewer FLOPs than ref).
// ---------------------------------------------------------------------------

#define T_TOK   8192
#define DDIM    512
#define HDIM    512
#define NEXP    8
#define NASSIGN (T_TOK * 2)

typedef _Float16 f16x8 __attribute__((ext_vector_type(8)));
typedef float    f32x4 __attribute__((ext_vector_type(4)));

// async global->LDS 16B copy (dest must be wave-uniform base + lane*16)
__device__ __forceinline__ void gld_lds16(const _Float16* g, _Float16* l) {
    __builtin_amdgcn_global_load_lds(
        (const __attribute__((address_space(1))) unsigned int*)g,
        (__attribute__((address_space(3))) unsigned int*)l,
        16, 0, 0);
}

// ---------------- weight transpose + fp32->f16 cast ------------------------
// z < 8 : W1[e] [D][H] -> W1t[e] [H][D] ; z >= 8 : W2[e] [H][D] -> W2t[e] [D][H]
__global__ void transw_kernel(const float* __restrict__ W1,
                              const float* __restrict__ W2,
                              _Float16* __restrict__ W1t,
                              _Float16* __restrict__ W2t) {
    __shared__ float tile[32][33];
    int z = blockIdx.z;
    const float* src;
    _Float16* dst;
    if (z < 8) { src = W1 + (size_t)z * 512 * 512; dst = W1t + (size_t)z * 512 * 512; }
    else       { src = W2 + (size_t)(z - 8) * 512 * 512; dst = W2t + (size_t)(z - 8) * 512 * 512; }
    int bx = blockIdx.x * 32;   // src col
    int by = blockIdx.y * 32;   // src row
    int tx = threadIdx.x, ty = threadIdx.y;
#pragma unroll
    for (int i = 0; i < 4; i++) {
        int r = by + ty + i * 8;
        tile[ty + i * 8][tx] = src[(size_t)r * 512 + bx + tx];
    }
    __syncthreads();
#pragma unroll
    for (int i = 0; i < 4; i++) {
        int r = bx + ty + i * 8;
        dst[(size_t)r * 512 + by + tx] = (_Float16)tile[tx][ty + i * 8];
    }
}

// ---------------- gating: fp64 logits, top-2, softmax; also cast x->f16 ----
// One token per wave; grid 2048 x 256.
__global__ void gate_kernel(const float* __restrict__ x,
                            const float* __restrict__ Wg,
                            _Float16* __restrict__ xh,
                            int* __restrict__ ei,
                            float* __restrict__ gw) {
    int lane = threadIdx.x & 63;
    int wave = threadIdx.x >> 6;
    int t = blockIdx.x * 4 + wave;

    const float* xr = x + (size_t)t * DDIM + lane * 8;
    float4 xa = *(const float4*)(xr);
    float4 xb = *(const float4*)(xr + 4);
    float xv[8] = {xa.x, xa.y, xa.z, xa.w, xb.x, xb.y, xb.z, xb.w};
    f16x8 hv;
#pragma unroll
    for (int j = 0; j < 8; j++) hv[j] = (_Float16)xv[j];
    *(f16x8*)(xh + (size_t)t * DDIM + lane * 8) = hv;

    double acc[NEXP];
#pragma unroll
    for (int e = 0; e < NEXP; e++) acc[e] = 0.0;
#pragma unroll
    for (int jj = 0; jj < 8; jj++) {
        int d = lane * 8 + jj;
        const float4* wr = (const float4*)(Wg + (size_t)d * NEXP);
        float4 w0 = wr[0], w1 = wr[1];
        float wv[8] = {w0.x, w0.y, w0.z, w0.w, w1.x, w1.y, w1.z, w1.w};
#pragma unroll
        for (int e = 0; e < NEXP; e++) acc[e] += (double)xv[jj] * (double)wv[e];
    }
    // reduce within groups of 8 lanes (all 8 experts)
#pragma unroll
    for (int off = 1; off < 8; off <<= 1) {
#pragma unroll
        for (int e = 0; e < NEXP; e++) acc[e] += __shfl_xor(acc[e], off, 64);
    }
    // distribute: lane l takes expert l&7
    double v = acc[0];
#pragma unroll
    for (int e = 1; e < NEXP; e++) if ((lane & 7) == e) v = acc[e];
    // reduce across the 8 groups
#pragma unroll
    for (int off = 8; off < 64; off <<= 1) v += __shfl_xor(v, off, 64);
    // broadcast all 8 logits to every lane; redundant top-2 everywhere
    double lv[NEXP];
#pragma unroll
    for (int e = 0; e < NEXP; e++) lv[e] = __shfl(v, e, 64);

    double v0 = -1e300; int i0 = 0;
#pragma unroll
    for (int e = 0; e < NEXP; e++) if (lv[e] > v0) { v0 = lv[e]; i0 = e; }
    double v1 = -1e300; int i1 = (i0 == 0) ? 1 : 0;
#pragma unroll
    for (int e = 0; e < NEXP; e++) if (e != i0 && lv[e] > v1) { v1 = lv[e]; i1 = e; }
    if (lane == 0) {
        double ex = exp(v1 - v0);   // <= 1
        float g0 = (float)(1.0 / (1.0 + ex));
        float g1 = (float)(ex / (1.0 + ex));
        ei[2 * t] = i0;  ei[2 * t + 1] = i1;
        gw[2 * t] = g0;  gw[2 * t + 1] = g1;
    }
}

// ---------------- histogram of expert assignments ---------------------------
__global__ void count_kernel(const int* __restrict__ ei,
                             int* __restrict__ counts) {
    __shared__ int lcnt[NEXP];
    if (threadIdx.x < NEXP) lcnt[threadIdx.x] = 0;
    __syncthreads();
    int i = blockIdx.x * 512 + threadIdx.x;   // grid 32 x 256 covers 16384
    atomicAdd(&lcnt[ei[i]], 1);
    atomicAdd(&lcnt[ei[i + 256]], 1);
    __syncthreads();
    if (threadIdx.x < NEXP) atomicAdd(&counts[threadIdx.x], lcnt[threadIdx.x]);
}

// ---------------- 8-entry exclusive prefix ---------------------------------
__global__ void prefix_kernel(const int* __restrict__ counts,
                              int* __restrict__ offsets,
                              int* __restrict__ cursor) {
    if (threadIdx.x == 0) {
        int s = 0;
        for (int e = 0; e < NEXP; e++) { offsets[e] = s; cursor[e] = s; s += counts[e]; }
    }
}

// ---------------- scatter: wave-aggregated bucket append -------------------
__global__ void scatter_kernel(const int* __restrict__ ei,
                               int* __restrict__ cursor,
                               int* __restrict__ rowtok,
                               int* __restrict__ pos) {
    int t = blockIdx.x * 256 + threadIdx.x;   // grid = 32 blocks, exact cover
    int lane = threadIdx.x & 63;
#pragma unroll
    for (int k = 0; k < 2; k++) {
        int s = 2 * t + k;
        int e = ei[s];
        int r = 0;
#pragma unroll
        for (int ex = 0; ex < NEXP; ex++) {
            unsigned long long mask = __ballot(e == ex);
            if (e == ex) {
                int leader = __ffsll((unsigned long long)mask) - 1;
                int cnt = __popcll(mask);
                unsigned long long below = mask & ((lane == 63) ? 0x7fffffffffffffffull
                                                                : ((1ull << lane) - 1ull));
                int base = 0;
                if (lane == leader) base = atomicAdd(&cursor[ex], cnt);
                base = __shfl(base, leader, 64);
                r = base + __popcll(below);
            }
        }
        rowtok[r] = s;
        pos[s] = r;
    }
}

// ---------------- grouped GEMM: C[r][n] = act(A[r] . Bt[n] + bias[n]) ------
// 128x128 tile, BK=32, 4 waves (2x2 of 64x64), mfma_f32_16x16x32_f16,
// async global->LDS staging (m97 structure).
template <bool GATHER, bool RELU>
__global__ __launch_bounds__(256) void gemm_tile(
    const _Float16* __restrict__ A,     // xh [T][512] (gather) or hb rows
    const _Float16* __restrict__ Bt,    // [E][N=512][K=512] f16 (pre-transposed)
    const float* __restrict__ bias,     // [E][512]
    const int* __restrict__ rowtok,     // assignment -> token*2+k (gather only)
    const int* __restrict__ counts,
    const int* __restrict__ offsets,
    _Float16* __restrict__ C)           // [NASSIGN][512]
{
    int e = blockIdx.z;
    int ne = counts[e];
    int m0 = blockIdx.y * 128;
    if (m0 >= ne) return;
    int off = offsets[e];
    int n0 = blockIdx.x * 128;
    const _Float16* Bte = Bt + (size_t)e * 512 * 512;

    __shared__ _Float16 As[128 * 32];
    __shared__ _Float16 Bs[128 * 32];

    int tid = threadIdx.x;
    int lane = tid & 63;
    int wave = tid >> 6;
    int wm = (wave >> 1) * 64;
    int wn = (wave & 1) * 64;
    int quad = lane >> 4;
    int l16 = lane & 15;

    int srow = tid >> 2;      // 0..63
    int schunk = tid & 3;     // 16B chunk within BK row

    int r0g = m0 + srow;
    int r1g = m0 + srow + 64;
    int cr0 = off + (r0g < ne ? r0g : ne - 1);
    int cr1 = off + (r1g < ne ? r1g : ne - 1);
    const _Float16* arow0;
    const _Float16* arow1;
    if (GATHER) {
        arow0 = A + (size_t)(rowtok[cr0] >> 1) * 512;
        arow1 = A + (size_t)(rowtok[cr1] >> 1) * 512;
    } else {
        arow0 = A + (size_t)cr0 * 512;
        arow1 = A + (size_t)cr1 * 512;
    }
    const _Float16* brow0 = Bte + (size_t)(n0 + srow) * 512;
    const _Float16* brow1 = Bte + (size_t)(n0 + srow + 64) * 512;

    f32x4 acc[4][4];
#pragma unroll
    for (int i = 0; i < 4; i++)
#pragma unroll
        for (int j = 0; j < 4; j++) {
            acc[i][j][0] = 0.f; acc[i][j][1] = 0.f;
            acc[i][j][2] = 0.f; acc[i][j][3] = 0.f;
        }

    for (int k0 = 0; k0 < 512; k0 += 32) {
        __syncthreads();   // previous iteration's LDS reads done
        // dest byte offset = tid*16 (+4KB for second row-batch): wave-uniform
        // base + lane*16 as global_load_lds requires.
        gld_lds16(arow0 + k0 + schunk * 8, &As[tid * 8]);
        gld_lds16(arow1 + k0 + schunk * 8, &As[tid * 8 + 64 * 32]);
        gld_lds16(brow0 + k0 + schunk * 8, &Bs[tid * 8]);
        gld_lds16(brow1 + k0 + schunk * 8, &Bs[tid * 8 + 64 * 32]);
        __syncthreads();   // drains vmcnt (compiler inserts) -> LDS visible

        f16x8 af[4], bf[4];
#pragma unroll
        for (int i = 0; i < 4; i++)
            af[i] = *(const f16x8*)(&As[(wm + i * 16 + l16) * 32 + quad * 8]);
#pragma unroll
        for (int j = 0; j < 4; j++)
            bf[j] = *(const f16x8*)(&Bs[(wn + j * 16 + l16) * 32 + quad * 8]);
#pragma unroll
        for (int i = 0; i < 4; i++)
#pragma unroll
            for (int j = 0; j < 4; j++)
                acc[i][j] = __builtin_amdgcn_mfma_f32_16x16x32_f16(af[i], bf[j], acc[i][j], 0, 0, 0);
    }

    // epilogue: D[row=quad*4+reg][col=l16]
    float bcol[4];
#pragma unroll
    for (int j = 0; j < 4; j++) bcol[j] = bias[(size_t)e * 512 + n0 + wn + j * 16 + l16];
#pragma unroll
    for (int i = 0; i < 4; i++) {
#pragma unroll
        for (int rr = 0; rr < 4; rr++) {
            int rg = m0 + wm + i * 16 + quad * 4 + rr;
            if (rg < ne) {
#pragma unroll
                for (int j = 0; j < 4; j++) {
                    float v = acc[i][j][rr] + bcol[j];
                    if (RELU) v = fmaxf(v, 0.0f);
                    C[(size_t)(off + rg) * 512 + n0 + wn + j * 16 + l16] = (_Float16)v;
                }
            }
        }
    }
}

// ---------------- LayerNorm + gate-weighted combine (1 wave / token) -------
__global__ void ln_combine_kernel(const _Float16* __restrict__ yb,
                                  const int* __restrict__ pos,
                                  const float* __restrict__ gw,
                                  const int* __restrict__ ei,
                                  const float* __restrict__ gamma,
                                  const float* __restrict__ beta,
                                  float* __restrict__ out) {
    int t = blockIdx.x * 4 + (threadIdx.x >> 6);
    int lane = threadIdx.x & 63;
    float o[8];
#pragma unroll
    for (int j = 0; j < 8; j++) o[j] = 0.0f;

#pragma unroll
    for (int k = 0; k < 2; k++) {
        int s = 2 * t + k;
        int r = pos[s];
        int e = ei[s];
        float w = gw[s];
        f16x8 v = *(const f16x8*)(yb + (size_t)r * 512 + lane * 8);
        float f[8];
        float sum = 0.f, sq = 0.f;
#pragma unroll
        for (int j = 0; j < 8; j++) { f[j] = (float)v[j]; sum += f[j]; sq += f[j] * f[j]; }
#pragma unroll
        for (int off = 1; off < 64; off <<= 1) {
            sum += __shfl_xor(sum, off, 64);
            sq  += __shfl_xor(sq, off, 64);
        }
        float mu = sum * (1.0f / 512.0f);
        float var = sq * (1.0f / 512.0f) - mu * mu;
        float rstd = rsqrtf(var + 1e-5f);
#pragma unroll
        for (int j = 0; j < 8; j++) {
            int d = lane * 8 + j;
            o[j] += w * ((f[j] - mu) * rstd * gamma[(size_t)e * 512 + d] + beta[(size_t)e * 512 + d]);
        }
    }
    float4* op = (float4*)(out + (size_t)t * 512 + lane * 8);
    op[0] = make_float4(o[0], o[1], o[2], o[3]);
    op[1] = make_float4(o[4], o[5], o[6], o[7]);
}

// ---------------------------------------------------------------------------
extern "C" void kernel_launch(void* const* d_in, const int* in_sizes, int n_in,
                              void* d_out, int out_size, void* d_ws, size_t ws_size,
                              hipStream_t stream) {
    const float* x     = (const float*)d_in[0];
    const float* Wg    = (const float*)d_in[1];
    const float* W1    = (const float*)d_in[2];
    const float* b1    = (const float*)d_in[3];
    const float* W2    = (const float*)d_in[4];
    const float* b2    = (const float*)d_in[5];
    const float* gamma = (const float*)d_in[6];
    const float* beta  = (const float*)d_in[7];
    float* out = (float*)d_out;

    // workspace carve-up (256B aligned)
    char* w = (char*)d_ws;
    size_t o = 0;
    auto alloc = [&](size_t bytes) -> void* {
        void* p = w + o;
        o += (bytes + 255) & ~(size_t)255;
        return p;
    };
    _Float16* xh  = (_Float16*)alloc((size_t)T_TOK * DDIM * 2);
    _Float16* W1t = (_Float16*)alloc((size_t)NEXP * DDIM * HDIM * 2);
    _Float16* W2t = (_Float16*)alloc((size_t)NEXP * DDIM * HDIM * 2);
    _Float16* hb  = (_Float16*)alloc((size_t)NASSIGN * HDIM * 2);
    _Float16* yb  = (_Float16*)alloc((size_t)NASSIGN * DDIM * 2);
    float* gw     = (float*)alloc((size_t)NASSIGN * 4);
    int* ei       = (int*)alloc((size_t)NASSIGN * 4);
    int* rowtok   = (int*)alloc((size_t)NASSIGN * 4);
    int* pos      = (int*)alloc((size_t)NASSIGN * 4);
    int* counts   = (int*)alloc(NEXP * 4);
    int* offsets  = (int*)alloc(NEXP * 4);
    int* cursor   = (int*)alloc(NEXP * 4);
    (void)ws_size; (void)n_in; (void)in_sizes; (void)out_size;

    hipMemsetAsync(counts, 0, NEXP * sizeof(int), stream);

    transw_kernel<<<dim3(16, 16, 16), dim3(32, 8), 0, stream>>>(W1, W2, W1t, W2t);
    gate_kernel<<<2048, 256, 0, stream>>>(x, Wg, xh, ei, gw);
    count_kernel<<<32, 256, 0, stream>>>(ei, counts);
    prefix_kernel<<<1, 64, 0, stream>>>(counts, offsets, cursor);
    scatter_kernel<<<32, 256, 0, stream>>>(ei, cursor, rowtok, pos);

    dim3 ggrid(4, 64, 8);   // n-tiles, max m-tiles (8192/128), experts
    gemm_tile<true, true><<<ggrid, 256, 0, stream>>>(xh, W1t, b1, rowtok, counts, offsets, hb);
    gemm_tile<false, false><<<ggrid, 256, 0, stream>>>(hb, W2t, b2, nullptr, counts, offsets, yb);

    ln_combine_kernel<<<2048, 256, 0, stream>>>(yb, pos, gw, ei, gamma, beta, out);
}